// Round 3
// baseline (129.957 us; speedup 1.0000x reference)
//
#include <hip/hip_runtime.h>
#include <math.h>

#define BB 32
#define SS 2048
#define DD 1024
#define NCH 32      // S-chunks (blocks) per b
#define WR 16       // rows per wave; 4 waves * 16 = 64 rows per block

// ws layout (floats):
//   energy : BB*SS          (256 KiB)
//   partial: BB*NCH*DD      (4 MiB)
//   ml     : BB*NCH*2       (8 KiB)

// K1: fused energy + online-softmax PV. One block per (b, 64-row chunk);
// each WAVE privately handles 16 rows across full D (lane owns 4 float4).
// No barriers in the hot loop; one block-merge at the end.
__global__ __launch_bounds__(256, 4) void fused_pass(const float* __restrict__ q,
                                                     const float* __restrict__ enc,
                                                     float* __restrict__ energy,
                                                     float* __restrict__ partial,
                                                     float* __restrict__ ml) {
    int blk = blockIdx.x;             // b*NCH + cb
    int b   = blk >> 5;
    int cb  = blk & (NCH - 1);
    int tid = threadIdx.x;
    int wid = tid >> 6;
    int ln  = tid & 63;

    __shared__ float sm[4], sl[4];
    __shared__ float sacc[4][DD];     // 16 KiB

    const float4* qp = (const float4*)(q + (size_t)b * DD);
    float4 qv[4];
#pragma unroll
    for (int k = 0; k < 4; ++k) qv[k] = qp[ln + 64 * k];

    int s0 = cb * 64 + wid * WR;
    const float4* base = (const float4*)enc;
    const size_t rowstride = (size_t)BB * DD / 4;              // float4 per s
    size_t idx0 = (size_t)(s0 * BB + b) * (DD / 4) + ln;

    float m = -1e30f, l = 0.f;
    float4 acc[4] = {{0,0,0,0},{0,0,0,0},{0,0,0,0},{0,0,0,0}};

#pragma unroll
    for (int i = 0; i < WR; ++i) {
        float4 v[4];
#pragma unroll
        for (int k = 0; k < 4; ++k)
            v[k] = base[idx0 + (size_t)i * rowstride + k * 64];

        float pd = 0.f;
#pragma unroll
        for (int k = 0; k < 4; ++k)
            pd += v[k].x * qv[k].x + v[k].y * qv[k].y
                + v[k].z * qv[k].z + v[k].w * qv[k].w;
#pragma unroll
        for (int off = 32; off > 0; off >>= 1)
            pd += __shfl_xor(pd, off, 64);

        if (ln == 0) energy[b * SS + s0 + i] = pd;

        float mn    = fmaxf(m, pd);
        float scale = __expf(m - mn);
        float p     = __expf(pd - mn);
        l = l * scale + p;
#pragma unroll
        for (int k = 0; k < 4; ++k) {
            acc[k].x = acc[k].x * scale + p * v[k].x;
            acc[k].y = acc[k].y * scale + p * v[k].y;
            acc[k].z = acc[k].z * scale + p * v[k].z;
            acc[k].w = acc[k].w * scale + p * v[k].w;
        }
        m = mn;
    }

    // block merge of 4 wave-partials
    if (ln == 0) { sm[wid] = m; sl[wid] = l; }
#pragma unroll
    for (int k = 0; k < 4; ++k)
        ((float4*)sacc[wid])[ln + 64 * k] = acc[k];
    __syncthreads();

    float M = fmaxf(fmaxf(sm[0], sm[1]), fmaxf(sm[2], sm[3]));
    float w0 = __expf(sm[0] - M), w1 = __expf(sm[1] - M);
    float w2 = __expf(sm[2] - M), w3 = __expf(sm[3] - M);
    float L = w0 * sl[0] + w1 * sl[1] + w2 * sl[2] + w3 * sl[3];

    float4 p0 = ((const float4*)sacc[0])[tid];
    float4 p1 = ((const float4*)sacc[1])[tid];
    float4 p2 = ((const float4*)sacc[2])[tid];
    float4 p3 = ((const float4*)sacc[3])[tid];
    float4 o;
    o.x = w0 * p0.x + w1 * p1.x + w2 * p2.x + w3 * p3.x;
    o.y = w0 * p0.y + w1 * p1.y + w2 * p2.y + w3 * p3.y;
    o.z = w0 * p0.z + w1 * p1.z + w2 * p2.z + w3 * p3.z;
    o.w = w0 * p0.w + w1 * p1.w + w2 * p2.w + w3 * p3.w;
    ((float4*)partial)[(size_t)blk * (DD / 4) + tid] = o;
    if (tid == 0) { ml[blk * 2] = M; ml[blk * 2 + 1] = L; }
}

// K2: merge NCH chunk partials per b -> values; then write scores.
__global__ __launch_bounds__(256) void merge_scores(const float* __restrict__ partial,
                                                    const float* __restrict__ ml,
                                                    const float* __restrict__ energy,
                                                    float* __restrict__ values,
                                                    float* __restrict__ scores) {
    int b   = blockIdx.x;
    int tid = threadIdx.x;
    __shared__ float sw[NCH];
    __shared__ float Lsh, Msh;

    if (tid == 0) {
        float M = -1e30f;
        for (int c = 0; c < NCH; ++c) M = fmaxf(M, ml[(b * NCH + c) * 2]);
        float L = 0.f;
        for (int c = 0; c < NCH; ++c) {
            float w = __expf(ml[(b * NCH + c) * 2] - M);
            sw[c] = w;
            L += w * ml[(b * NCH + c) * 2 + 1];
        }
        Msh = M; Lsh = L;
    }
    __syncthreads();
    float M = Msh, inv = 1.f / Lsh;

    float4 acc = {0.f, 0.f, 0.f, 0.f};
    for (int c = 0; c < NCH; ++c) {
        float w = sw[c];
        float4 p = ((const float4*)partial)[(size_t)(b * NCH + c) * (DD / 4) + tid];
        acc.x += w * p.x; acc.y += w * p.y; acc.z += w * p.z; acc.w += w * p.w;
    }
    acc.x *= inv; acc.y *= inv; acc.z *= inv; acc.w *= inv;
    ((float4*)values)[(size_t)b * (DD / 4) + tid] = acc;

#pragma unroll
    for (int k = 0; k < 8; ++k) {
        int idx = b * SS + k * 256 + tid;
        scores[idx] = __expf(energy[idx] - M) * inv;
    }
}

extern "C" void kernel_launch(void* const* d_in, const int* in_sizes, int n_in,
                              void* d_out, int out_size, void* d_ws, size_t ws_size,
                              hipStream_t stream) {
    const float* q   = (const float*)d_in[0];   // (1,B,D)
    const float* enc = (const float*)d_in[1];   // (S,B,D)
    float* out    = (float*)d_out;
    float* values = out;                        // (B,D)
    float* scores = out + BB * DD;              // (B,S)

    float* energy  = (float*)d_ws;              // BB*SS
    float* partial = energy + BB * SS;          // BB*NCH*DD
    float* ml      = partial + (size_t)BB * NCH * DD;  // BB*NCH*2

    fused_pass<<<BB * NCH, 256, 0, stream>>>(q, enc, energy, partial, ml);
    merge_scores<<<BB, 256, 0, stream>>>(partial, ml, energy, values, scores);
}

// Round 4
// 76.281 us; speedup vs baseline: 1.7037x; 1.7037x over previous
//
#include <hip/hip_runtime.h>
#include <math.h>

#define BB 32
#define SS 2048
#define DD 1024
#define NCH 32      // S-chunks (blocks) per b
#define G 8         // rows per group
#define NG 8        // groups per block (G*NG = 64 rows per block)

// ws layout (floats):
//   energy : BB*SS          (256 KiB)
//   partial: BB*NCH*DD      (4 MiB)
//   ml     : BB*NCH*2       (8 KiB)

// K1: fused energy + online-softmax PV. One block per (b, 64-row chunk).
// Thread owns one float4 of D (256 threads x 4 = 1024). Rows processed in
// groups of 8 with a 2-deep load pipeline; one barrier per group.
__global__ __launch_bounds__(256) void fused_pass(const float* __restrict__ q,
                                                  const float* __restrict__ enc,
                                                  float* __restrict__ energy,
                                                  float* __restrict__ partial,
                                                  float* __restrict__ ml) {
    int blk = blockIdx.x;             // b*NCH + cb
    int b   = blk >> 5;
    int cb  = blk & (NCH - 1);
    int tid = threadIdx.x;
    int wid = tid >> 6;
    int ln  = tid & 63;

    __shared__ float red[2][4][G];

    float4 qv = ((const float4*)(q + (size_t)b * DD))[tid];

    int s0 = cb * (G * NG);
    const float4* base = (const float4*)enc;
    const size_t rs = (size_t)BB * (DD / 4);            // float4 per s step
    size_t idx0 = (size_t)(s0 * BB + b) * (DD / 4) + tid;

    float m = -1e30f, l = 0.f;
    float4 acc = {0.f, 0.f, 0.f, 0.f};
    float4 v[2][G];

#pragma unroll
    for (int i = 0; i < G; ++i) v[0][i] = base[idx0 + (size_t)i * rs];

#pragma unroll
    for (int gp = 0; gp < NG; ++gp) {
        const int cur = gp & 1, nxt = cur ^ 1;
        if (gp + 1 < NG) {
#pragma unroll
            for (int i = 0; i < G; ++i)
                v[nxt][i] = base[idx0 + (size_t)((gp + 1) * G + i) * rs];
        }

        // 8 dots, reduced wave-locally with cross-row ILP
        float pd[G];
#pragma unroll
        for (int i = 0; i < G; ++i) {
            float4 vv = v[cur][i];
            pd[i] = vv.x * qv.x + vv.y * qv.y + vv.z * qv.z + vv.w * qv.w;
        }
#pragma unroll
        for (int off = 32; off > 0; off >>= 1)
#pragma unroll
            for (int i = 0; i < G; ++i)
                pd[i] += __shfl_xor(pd[i], off, 64);

        if (ln == 0) {
#pragma unroll
            for (int i = 0; i < G; ++i) red[cur][wid][i] = pd[i];
        }
        __syncthreads();

        float e[G];
#pragma unroll
        for (int i = 0; i < G; ++i)
            e[i] = red[cur][0][i] + red[cur][1][i] + red[cur][2][i] + red[cur][3][i];

        if (tid < G) {
            float ee = red[cur][0][tid] + red[cur][1][tid]
                     + red[cur][2][tid] + red[cur][3][tid];
            energy[b * SS + s0 + gp * G + tid] = ee;
        }

        // online softmax update (uniform across all threads; m,l identical)
#pragma unroll
        for (int i = 0; i < G; ++i) {
            float mn    = fmaxf(m, e[i]);
            float scale = __expf(m - mn);
            float p     = __expf(e[i] - mn);
            l = l * scale + p;
            float4 vv = v[cur][i];
            acc.x = acc.x * scale + p * vv.x;
            acc.y = acc.y * scale + p * vv.y;
            acc.z = acc.z * scale + p * vv.z;
            acc.w = acc.w * scale + p * vv.w;
            m = mn;
        }
    }

    ((float4*)(partial + (size_t)blk * DD))[tid] = acc;
    if (tid == 0) { ml[blk * 2] = m; ml[blk * 2 + 1] = l; }
}

// K2: merge NCH chunk partials per b -> values; then write scores.
__global__ __launch_bounds__(256) void merge_scores(const float* __restrict__ partial,
                                                    const float* __restrict__ ml,
                                                    const float* __restrict__ energy,
                                                    float* __restrict__ values,
                                                    float* __restrict__ scores) {
    int b   = blockIdx.x;
    int tid = threadIdx.x;
    __shared__ float sw[NCH];
    __shared__ float Lsh, Msh;

    if (tid == 0) {
        float M = -1e30f;
        for (int c = 0; c < NCH; ++c) M = fmaxf(M, ml[(b * NCH + c) * 2]);
        float L = 0.f;
        for (int c = 0; c < NCH; ++c) {
            float w = __expf(ml[(b * NCH + c) * 2] - M);
            sw[c] = w;
            L += w * ml[(b * NCH + c) * 2 + 1];
        }
        Msh = M; Lsh = L;
    }
    __syncthreads();
    float M = Msh, inv = 1.f / Lsh;

    float4 acc = {0.f, 0.f, 0.f, 0.f};
    for (int c = 0; c < NCH; ++c) {
        float w = sw[c];
        float4 p = ((const float4*)partial)[(size_t)(b * NCH + c) * (DD / 4) + tid];
        acc.x += w * p.x; acc.y += w * p.y; acc.z += w * p.z; acc.w += w * p.w;
    }
    acc.x *= inv; acc.y *= inv; acc.z *= inv; acc.w *= inv;
    ((float4*)values)[(size_t)b * (DD / 4) + tid] = acc;

#pragma unroll
    for (int k = 0; k < 8; ++k) {
        int idx = b * SS + k * 256 + tid;
        scores[idx] = __expf(energy[idx] - M) * inv;
    }
}

extern "C" void kernel_launch(void* const* d_in, const int* in_sizes, int n_in,
                              void* d_out, int out_size, void* d_ws, size_t ws_size,
                              hipStream_t stream) {
    const float* q   = (const float*)d_in[0];   // (1,B,D)
    const float* enc = (const float*)d_in[1];   // (S,B,D)
    float* out    = (float*)d_out;
    float* values = out;                        // (B,D)
    float* scores = out + BB * DD;              // (B,S)

    float* energy  = (float*)d_ws;              // BB*SS
    float* partial = energy + BB * SS;          // BB*NCH*DD
    float* ml      = partial + (size_t)BB * NCH * DD;  // BB*NCH*2

    fused_pass<<<BB * NCH, 256, 0, stream>>>(q, enc, energy, partial, ml);
    merge_scores<<<BB, 256, 0, stream>>>(partial, ml, energy, values, scores);
}

// Round 5
// 54.999 us; speedup vs baseline: 2.3629x; 1.3870x over previous
//
#include <hip/hip_runtime.h>
#include <math.h>

#define BB 32
#define SS 2048
#define DD 1024

// ws layout (floats), nch = chunks per b (64 preferred, 32 fallback):
//   energy : BB*SS
//   partial: BB*nch*DD
//   ml     : BB*nch*2

// K1: fused energy + online-softmax PV. One block per (b, chunk of SS/NCH rows).
// Thread owns one float4 of D (256 x 4 = 1024). 1-row prefetch, one barrier
// per row (double-buffered LDS reduce). All threads carry identical (m,l).
template <int NCH>
__global__ __launch_bounds__(256, 8) void fused_pass(const float* __restrict__ q,
                                                     const float* __restrict__ enc,
                                                     float* __restrict__ energy,
                                                     float* __restrict__ partial,
                                                     float* __restrict__ ml) {
    constexpr int CHS = SS / NCH;
    int blk = blockIdx.x;             // b*NCH + cb
    int b   = blk / NCH;
    int cb  = blk % NCH;
    int tid = threadIdx.x;
    int wid = tid >> 6;
    int ln  = tid & 63;

    __shared__ float red[2][4];

    float4 qv = ((const float4*)(q + (size_t)b * DD))[tid];

    int s0 = cb * CHS;
    const float4* base = (const float4*)enc;
    const size_t rs = (size_t)BB * (DD / 4);            // float4 per s step
    size_t idx = (size_t)(s0 * BB + b) * (DD / 4) + tid;

    float m = -1e30f, l = 0.f;
    float4 acc = {0.f, 0.f, 0.f, 0.f};
    float4 v = base[idx];

    for (int i = 0; i < CHS; ++i) {
        float4 vn = {0.f, 0.f, 0.f, 0.f};
        if (i + 1 < CHS) vn = base[idx + (size_t)(i + 1) * rs];  // prefetch

        float pd = v.x * qv.x + v.y * qv.y + v.z * qv.z + v.w * qv.w;
#pragma unroll
        for (int off = 32; off > 0; off >>= 1)
            pd += __shfl_xor(pd, off, 64);
        if (ln == 0) red[i & 1][wid] = pd;
        __syncthreads();
        float e = red[i & 1][0] + red[i & 1][1] + red[i & 1][2] + red[i & 1][3];

        if (tid == 0) energy[b * SS + s0 + i] = e;

        float mn    = fmaxf(m, e);
        float scale = __expf(m - mn);
        float p     = __expf(e - mn);
        l = l * scale + p;
        acc.x = acc.x * scale + p * v.x;
        acc.y = acc.y * scale + p * v.y;
        acc.z = acc.z * scale + p * v.z;
        acc.w = acc.w * scale + p * v.w;
        m = mn;
        v = vn;
    }

    ((float4*)(partial + (size_t)blk * DD))[tid] = acc;
    if (tid == 0) { ml[blk * 2] = m; ml[blk * 2 + 1] = l; }
}

// K2: merge nch chunk partials per b -> values; write scores.
// Grid = BB*4: each block owns a quarter of D and a quarter of S.
__global__ __launch_bounds__(256) void merge_scores(const float* __restrict__ partial,
                                                    const float* __restrict__ ml,
                                                    const float* __restrict__ energy,
                                                    float* __restrict__ values,
                                                    float* __restrict__ scores,
                                                    int nch) {
    int blk  = blockIdx.x;
    int b    = blk >> 2;
    int quad = blk & 3;
    int tid  = threadIdx.x;
    __shared__ float sm[64], sl[64];

    if (tid < nch) {
        sm[tid] = ml[(b * nch + tid) * 2];
        sl[tid] = ml[(b * nch + tid) * 2 + 1];
    }
    __syncthreads();

    float M = -1e30f;
    for (int c = 0; c < nch; ++c) M = fmaxf(M, sm[c]);

    int d = quad * 256 + tid;
    float L = 0.f, acc = 0.f;
    for (int c = 0; c < nch; ++c) {
        float w = __expf(sm[c] - M);
        L += w * sl[c];
        acc += w * partial[(size_t)(b * nch + c) * DD + d];
    }
    float inv = 1.f / L;
    values[b * DD + d] = acc * inv;

#pragma unroll
    for (int k = 0; k < 2; ++k) {
        int idx = b * SS + quad * 512 + k * 256 + tid;
        scores[idx] = __expf(energy[idx] - M) * inv;
    }
}

extern "C" void kernel_launch(void* const* d_in, const int* in_sizes, int n_in,
                              void* d_out, int out_size, void* d_ws, size_t ws_size,
                              hipStream_t stream) {
    const float* q   = (const float*)d_in[0];   // (1,B,D)
    const float* enc = (const float*)d_in[1];   // (S,B,D)
    float* out    = (float*)d_out;
    float* values = out;                        // (B,D)
    float* scores = out + BB * DD;              // (B,S)

    size_t need64 = ((size_t)BB * SS + (size_t)BB * 64 * DD + (size_t)BB * 64 * 2)
                    * sizeof(float);
    int nch = (ws_size >= need64) ? 64 : 32;

    float* energy  = (float*)d_ws;                         // BB*SS
    float* partial = energy + BB * SS;                     // BB*nch*DD
    float* ml      = partial + (size_t)BB * nch * DD;      // BB*nch*2

    if (nch == 64)
        fused_pass<64><<<BB * 64, 256, 0, stream>>>(q, enc, energy, partial, ml);
    else
        fused_pass<32><<<BB * 32, 256, 0, stream>>>(q, enc, energy, partial, ml);
    merge_scores<<<BB * 4, 256, 0, stream>>>(partial, ml, energy, values, scores, nch);
}